// Round 1
// baseline (1010.982 us; speedup 1.0000x reference)
//
#include <hip/hip_runtime.h>

#define NCOL 64
#define EPSV 1e-5f

// ---------------- CSR build ----------------

__global__ void hist_kernel(const int* __restrict__ dst, int* __restrict__ cnt, int E) {
    int i = blockIdx.x * blockDim.x + threadIdx.x;
    if (i < E) atomicAdd(&cnt[dst[i]], 1);
}

// Wave-aggregated segment allocation: one global atomic per wave (~1.6K total).
__global__ void alloc_kernel(const int* __restrict__ cnt, int* __restrict__ start,
                             int* __restrict__ fillcur, int* __restrict__ cursor, int n) {
    int i = blockIdx.x * blockDim.x + threadIdx.x;
    int lane = threadIdx.x & 63;
    int c = (i < n) ? cnt[i] : 0;
    int pre = c;
    for (int d = 1; d < 64; d <<= 1) {
        int t = __shfl_up(pre, d);
        if (lane >= d) pre += t;
    }
    int excl = pre - c;
    int total = __shfl(pre, 63);
    int base = 0;
    if (lane == 0) base = atomicAdd(cursor, total);
    base = __shfl(base, 0);
    if (i < n) { start[i] = base + excl; fillcur[i] = base + excl; }
}

__global__ void fill_kernel(const int* __restrict__ src, const int* __restrict__ dst,
                            int* __restrict__ fillcur, int* __restrict__ col, int E) {
    int i = blockIdx.x * blockDim.x + threadIdx.x;
    if (i < E) {
        int p = atomicAdd(&fillcur[dst[i]], 1);
        col[p] = src[i];
    }
}

// ---------------- fused SAGE layer: mean-aggregate + dual GEMM + bias ----------------
// One wave per node; lane = output column. Previous layer's BN+ReLU applied on the fly.

template <int DIN, bool PRENORM>
__global__ __launch_bounds__(256) void fused_layer(
    const float* __restrict__ xin, const float* __restrict__ scale, const float* __restrict__ shift,
    const int* __restrict__ col, const int* __restrict__ start, const int* __restrict__ cnt,
    const float* __restrict__ Wl, const float* __restrict__ bl, const float* __restrict__ Wr,
    float* __restrict__ hout, int n)
{
    __shared__ float sWl[DIN * NCOL];
    __shared__ float sWr[DIN * NCOL];
    for (int i = threadIdx.x; i < DIN * NCOL; i += 256) { sWl[i] = Wl[i]; sWr[i] = Wr[i]; }
    __syncthreads();

    int wave = threadIdx.x >> 6;
    int lane = threadIdx.x & 63;
    int node = blockIdx.x * 4 + wave;
    if (node >= n) return;

    float scl = 1.f, shf = 0.f;
    if (PRENORM) { scl = scale[lane]; shf = shift[lane]; }

    float xself = 0.f;
    if (lane < DIN) {
        xself = xin[(size_t)node * DIN + lane];
        if (PRENORM) xself = fmaxf(xself * scl + shf, 0.f);
    }

    int s0 = start[node];
    int deg = cnt[node];
    float acc = 0.f;
    for (int j0 = 0; j0 < deg; j0 += 64) {
        int m = min(64, deg - j0);
        int myidx = (j0 + lane < deg) ? col[s0 + j0 + lane] : 0;
        for (int j = 0; j < m; ++j) {
            int srcn = __shfl(myidx, j);
            float v = 0.f;
            if (lane < DIN) {
                v = xin[(size_t)srcn * DIN + lane];
                if (PRENORM) v = fmaxf(v * scl + shf, 0.f);
            }
            acc += v;
        }
    }
    acc *= 1.f / (float)max(deg, 1);

    float h = bl[lane];
#pragma unroll
    for (int k = 0; k < DIN; ++k) {
        float ak = __shfl(acc, k);
        float xk = __shfl(xself, k);
        h += ak * sWl[k * NCOL + lane] + xk * sWr[k * NCOL + lane];
    }
    hout[(size_t)node * NCOL + lane] = h;
}

// ---------------- BN statistics ----------------

__global__ __launch_bounds__(256) void bn_stats(const float* __restrict__ h,
                                                float* __restrict__ sums, int n) {
    int lane = threadIdx.x & 63;
    int wave = threadIdx.x >> 6;
    float s = 0.f, s2 = 0.f;
    for (int r = blockIdx.x * 4 + wave; r < n; r += gridDim.x * 4) {
        float v = h[(size_t)r * 64 + lane];
        s += v; s2 += v * v;
    }
    __shared__ float ls[256], ls2[256];
    ls[threadIdx.x] = s; ls2[threadIdx.x] = s2;
    __syncthreads();
    if (threadIdx.x < 64) {
        s = ls[threadIdx.x] + ls[threadIdx.x + 64] + ls[threadIdx.x + 128] + ls[threadIdx.x + 192];
        s2 = ls2[threadIdx.x] + ls2[threadIdx.x + 64] + ls2[threadIdx.x + 128] + ls2[threadIdx.x + 192];
        atomicAdd(&sums[threadIdx.x], s);
        atomicAdd(&sums[64 + threadIdx.x], s2);
    }
}

__global__ void bn_finalize(const float* __restrict__ sums, const float* __restrict__ g,
                            const float* __restrict__ be, float* __restrict__ scale,
                            float* __restrict__ shift, int n) {
    int c = threadIdx.x;
    if (c < 64) {
        float inv_n = 1.f / (float)n;
        float mu = sums[c] * inv_n;
        float var = sums[64 + c] * inv_n - mu * mu;
        float sc = g[c] * rsqrtf(var + EPSV);
        scale[c] = sc;
        shift[c] = be[c] - mu * sc;
    }
}

// ---------------- output head: relu(BN(h)) @ Wo + bo ----------------

__global__ __launch_bounds__(256) void out_kernel(const float* __restrict__ h,
                                                  const float* __restrict__ scale,
                                                  const float* __restrict__ shift,
                                                  const float* __restrict__ Wo,
                                                  const float* __restrict__ bo,
                                                  float* __restrict__ out, int n) {
    int lane = threadIdx.x & 63;
    int wave = threadIdx.x >> 6;
    int node = blockIdx.x * 4 + wave;
    if (node >= n) return;
    float v = h[(size_t)node * 64 + lane];
    v = fmaxf(v * scale[lane] + shift[lane], 0.f);
    float p = v * Wo[lane];
    for (int d = 32; d > 0; d >>= 1) p += __shfl_xor(p, d);
    if (lane == 0) out[node] = p + bo[0];
}

// ---------------- launch ----------------

extern "C" void kernel_launch(void* const* d_in, const int* in_sizes, int n_in,
                              void* d_out, int out_size, void* d_ws, size_t ws_size,
                              hipStream_t stream) {
    const float* x   = (const float*)d_in[0];
    const int*   ei  = (const int*)d_in[1];
    const float* Wl0 = (const float*)d_in[2];
    const float* bl0 = (const float*)d_in[3];
    const float* Wr0 = (const float*)d_in[4];
    const float* g0  = (const float*)d_in[5];
    const float* be0 = (const float*)d_in[6];
    const float* Wl1 = (const float*)d_in[7];
    const float* bl1 = (const float*)d_in[8];
    const float* Wr1 = (const float*)d_in[9];
    const float* g1  = (const float*)d_in[10];
    const float* be1 = (const float*)d_in[11];
    const float* Wl2 = (const float*)d_in[12];
    const float* bl2 = (const float*)d_in[13];
    const float* Wr2 = (const float*)d_in[14];
    const float* g2  = (const float*)d_in[15];
    const float* be2 = (const float*)d_in[16];
    const float* Wo  = (const float*)d_in[17];
    const float* bo  = (const float*)d_in[18];

    const int N = in_sizes[0] / 7;
    const int E = in_sizes[1] / 2;
    const int* srcp = ei;
    const int* dstp = ei + E;

    char* ws = (char*)d_ws;
    size_t off = 0;
    auto walloc = [&](size_t bytes) -> void* {
        void* p = ws + off;
        off = (off + bytes + 255) & ~(size_t)255;
        return p;
    };
    int*   cnt     = (int*)walloc((size_t)(N + 1) * sizeof(int));  // cursor at cnt[N]
    int*   cursor  = cnt + N;
    int*   start   = (int*)walloc((size_t)N * sizeof(int));
    int*   fillcur = (int*)walloc((size_t)N * sizeof(int));
    int*   col     = (int*)walloc((size_t)E * sizeof(int));
    float* sums    = (float*)walloc(3 * 128 * sizeof(float));
    float* scale   = (float*)walloc(3 * 64 * sizeof(float));
    float* shift   = (float*)walloc(3 * 64 * sizeof(float));
    float* h0      = (float*)walloc((size_t)N * 64 * sizeof(float));
    float* h1      = (float*)walloc((size_t)N * 64 * sizeof(float));

    hipMemsetAsync(cnt, 0, (size_t)(N + 1) * sizeof(int), stream);
    hipMemsetAsync(sums, 0, 3 * 128 * sizeof(float), stream);

    const int tb = 256;
    hist_kernel<<<(E + tb - 1) / tb, tb, 0, stream>>>(dstp, cnt, E);
    alloc_kernel<<<(N + tb - 1) / tb, tb, 0, stream>>>(cnt, start, fillcur, cursor, N);
    fill_kernel<<<(E + tb - 1) / tb, tb, 0, stream>>>(srcp, dstp, fillcur, col, E);

    const int gb = (N + 3) / 4;

    fused_layer<7, false><<<gb, 256, 0, stream>>>(x, nullptr, nullptr, col, start, cnt,
                                                  Wl0, bl0, Wr0, h0, N);
    bn_stats<<<1024, 256, 0, stream>>>(h0, sums, N);
    bn_finalize<<<1, 64, 0, stream>>>(sums, g0, be0, scale, shift, N);

    fused_layer<64, true><<<gb, 256, 0, stream>>>(h0, scale, shift, col, start, cnt,
                                                  Wl1, bl1, Wr1, h1, N);
    bn_stats<<<1024, 256, 0, stream>>>(h1, sums + 128, N);
    bn_finalize<<<1, 64, 0, stream>>>(sums + 128, g1, be1, scale + 64, shift + 64, N);

    fused_layer<64, true><<<gb, 256, 0, stream>>>(h1, scale + 64, shift + 64, col, start, cnt,
                                                  Wl2, bl2, Wr2, h0, N);
    bn_stats<<<1024, 256, 0, stream>>>(h0, sums + 256, N);
    bn_finalize<<<1, 64, 0, stream>>>(sums + 256, g2, be2, scale + 128, shift + 128, N);

    out_kernel<<<gb, 256, 0, stream>>>(h0, scale + 128, shift + 128, Wo, bo, (float*)d_out, N);
}

// Round 2
// 794.148 us; speedup vs baseline: 1.2730x; 1.2730x over previous
//
#include <hip/hip_runtime.h>

#define NCOL 64
#define EPSV 1e-5f

// ---------------- CSR build ----------------

__global__ void hist_kernel(const int* __restrict__ dst, int* __restrict__ cnt, int E) {
    int i = blockIdx.x * blockDim.x + threadIdx.x;
    if (i < E) atomicAdd(&cnt[dst[i]], 1);
}

// Wave-aggregated segment allocation: one global atomic per wave (~1.6K total).
__global__ void alloc_kernel(const int* __restrict__ cnt, int* __restrict__ start,
                             int* __restrict__ fillcur, int* __restrict__ cursor, int n) {
    int i = blockIdx.x * blockDim.x + threadIdx.x;
    int lane = threadIdx.x & 63;
    int c = (i < n) ? cnt[i] : 0;
    int pre = c;
    for (int d = 1; d < 64; d <<= 1) {
        int t = __shfl_up(pre, d);
        if (lane >= d) pre += t;
    }
    int excl = pre - c;
    int total = __shfl(pre, 63);
    int base = 0;
    if (lane == 0) base = atomicAdd(cursor, total);
    base = __shfl(base, 0);
    if (i < n) { start[i] = base + excl; fillcur[i] = base + excl; }
}

__global__ void fill_kernel(const int* __restrict__ src, const int* __restrict__ dst,
                            int* __restrict__ fillcur, int* __restrict__ col, int E) {
    int i = blockIdx.x * blockDim.x + threadIdx.x;
    if (i < E) {
        int p = atomicAdd(&fillcur[dst[i]], 1);
        col[p] = src[i];
    }
}

// ---------------- fused SAGE layer: mean-aggregate + dual GEMM + bias ----------------
// One wave per node; lane = output column. Previous layer's BN+ReLU applied on the fly.
// Gather is batched 8 neighbors at a time: 8 scalar index loads + 8 independent
// vector loads in flight -> ~8x memory-level parallelism vs serial shfl chain.

template <int DIN, bool PRENORM>
__global__ __launch_bounds__(512) void fused_layer(
    const float* __restrict__ xin, const float* __restrict__ scale, const float* __restrict__ shift,
    const int* __restrict__ col, const int* __restrict__ start, const int* __restrict__ cnt,
    const float* __restrict__ Wl, const float* __restrict__ bl, const float* __restrict__ Wr,
    float* __restrict__ hout, int n)
{
    __shared__ float sWl[DIN * NCOL];
    __shared__ float sWr[DIN * NCOL];
    for (int i = threadIdx.x; i < DIN * NCOL; i += 512) { sWl[i] = Wl[i]; sWr[i] = Wr[i]; }
    __syncthreads();

    int lane = threadIdx.x & 63;
    int node = blockIdx.x * 8 + (threadIdx.x >> 6);
    if (node >= n) return;
    node = __builtin_amdgcn_readfirstlane(node);

    float scl = 1.f, shf = 0.f;
    if (PRENORM) { scl = scale[lane]; shf = shift[lane]; }

    float xself = 0.f;
    if (lane < DIN) {
        xself = xin[(size_t)node * DIN + lane];
        if (PRENORM) xself = fmaxf(xself * scl + shf, 0.f);
    }

    int s0  = __builtin_amdgcn_readfirstlane(start[node]);
    int deg = __builtin_amdgcn_readfirstlane(cnt[node]);
    const int* __restrict__ cp = col + s0;

    float a0 = 0.f, a1 = 0.f, a2 = 0.f, a3 = 0.f;
    float a4 = 0.f, a5 = 0.f, a6 = 0.f, a7 = 0.f;

    for (int j0 = 0; j0 < deg; j0 += 8) {
        // May over-read (within this node's CSR neighborhood-array or the ws
        // slack after it); indices are clamped and values predicated to 0.
        int i0 = cp[j0 + 0], i1 = cp[j0 + 1], i2 = cp[j0 + 2], i3 = cp[j0 + 3];
        int i4 = cp[j0 + 4], i5 = cp[j0 + 5], i6 = cp[j0 + 6], i7 = cp[j0 + 7];
        i0 = min(max(i0, 0), n - 1); i1 = min(max(i1, 0), n - 1);
        i2 = min(max(i2, 0), n - 1); i3 = min(max(i3, 0), n - 1);
        i4 = min(max(i4, 0), n - 1); i5 = min(max(i5, 0), n - 1);
        i6 = min(max(i6, 0), n - 1); i7 = min(max(i7, 0), n - 1);
        float v0 = 0.f, v1 = 0.f, v2 = 0.f, v3 = 0.f;
        float v4 = 0.f, v5 = 0.f, v6 = 0.f, v7 = 0.f;
        if (lane < DIN) {
            v0 = xin[(size_t)i0 * DIN + lane]; v1 = xin[(size_t)i1 * DIN + lane];
            v2 = xin[(size_t)i2 * DIN + lane]; v3 = xin[(size_t)i3 * DIN + lane];
            v4 = xin[(size_t)i4 * DIN + lane]; v5 = xin[(size_t)i5 * DIN + lane];
            v6 = xin[(size_t)i6 * DIN + lane]; v7 = xin[(size_t)i7 * DIN + lane];
        }
        if (PRENORM) {
            v0 = fmaxf(v0 * scl + shf, 0.f); v1 = fmaxf(v1 * scl + shf, 0.f);
            v2 = fmaxf(v2 * scl + shf, 0.f); v3 = fmaxf(v3 * scl + shf, 0.f);
            v4 = fmaxf(v4 * scl + shf, 0.f); v5 = fmaxf(v5 * scl + shf, 0.f);
            v6 = fmaxf(v6 * scl + shf, 0.f); v7 = fmaxf(v7 * scl + shf, 0.f);
        }
        a0 += v0;
        a1 += (j0 + 1 < deg) ? v1 : 0.f;
        a2 += (j0 + 2 < deg) ? v2 : 0.f;
        a3 += (j0 + 3 < deg) ? v3 : 0.f;
        a4 += (j0 + 4 < deg) ? v4 : 0.f;
        a5 += (j0 + 5 < deg) ? v5 : 0.f;
        a6 += (j0 + 6 < deg) ? v6 : 0.f;
        a7 += (j0 + 7 < deg) ? v7 : 0.f;
    }
    float acc = (((a0 + a1) + (a2 + a3)) + ((a4 + a5) + (a6 + a7))) * (1.f / (float)max(deg, 1));

    float h = bl[lane];
#pragma unroll
    for (int k = 0; k < DIN; ++k) {
        float ak = __shfl(acc, k);
        float xk = __shfl(xself, k);
        h += ak * sWl[k * NCOL + lane] + xk * sWr[k * NCOL + lane];
    }
    hout[(size_t)node * NCOL + lane] = h;
}

// ---------------- BN statistics ----------------

__global__ __launch_bounds__(256) void bn_stats(const float* __restrict__ h,
                                                float* __restrict__ sums, int n) {
    __shared__ float ls[128];
    if (threadIdx.x < 128) ls[threadIdx.x] = 0.f;
    __syncthreads();
    size_t total = (size_t)n * 64;
    size_t stride = (size_t)gridDim.x * 1024;
    float s0 = 0.f, s1 = 0.f, s2 = 0.f, s3 = 0.f;
    float q0 = 0.f, q1 = 0.f, q2 = 0.f, q3 = 0.f;
    for (size_t i = (size_t)blockIdx.x * 1024 + (size_t)threadIdx.x * 4; i < total; i += stride) {
        float4 v = *reinterpret_cast<const float4*>(h + i);
        s0 += v.x; q0 += v.x * v.x;
        s1 += v.y; q1 += v.y * v.y;
        s2 += v.z; q2 += v.z * v.z;
        s3 += v.w; q3 += v.w * v.w;
    }
    int c = (threadIdx.x * 4) & 63;
    atomicAdd(&ls[c + 0], s0); atomicAdd(&ls[c + 1], s1);
    atomicAdd(&ls[c + 2], s2); atomicAdd(&ls[c + 3], s3);
    atomicAdd(&ls[64 + c + 0], q0); atomicAdd(&ls[64 + c + 1], q1);
    atomicAdd(&ls[64 + c + 2], q2); atomicAdd(&ls[64 + c + 3], q3);
    __syncthreads();
    if (threadIdx.x < 128) atomicAdd(&sums[threadIdx.x], ls[threadIdx.x]);
}

__global__ void bn_finalize(const float* __restrict__ sums, const float* __restrict__ g,
                            const float* __restrict__ be, float* __restrict__ scale,
                            float* __restrict__ shift, int n) {
    int c = threadIdx.x;
    if (c < 64) {
        float inv_n = 1.f / (float)n;
        float mu = sums[c] * inv_n;
        float var = sums[64 + c] * inv_n - mu * mu;
        float sc = g[c] * rsqrtf(var + EPSV);
        scale[c] = sc;
        shift[c] = be[c] - mu * sc;
    }
}

// ---------------- output head: relu(BN(h)) @ Wo + bo ----------------

__global__ __launch_bounds__(256) void out_kernel(const float* __restrict__ h,
                                                  const float* __restrict__ scale,
                                                  const float* __restrict__ shift,
                                                  const float* __restrict__ Wo,
                                                  const float* __restrict__ bo,
                                                  float* __restrict__ out, int n) {
    int lane = threadIdx.x & 63;
    int wave = threadIdx.x >> 6;
    int node = blockIdx.x * 4 + wave;
    if (node >= n) return;
    float v = h[(size_t)node * 64 + lane];
    v = fmaxf(v * scale[lane] + shift[lane], 0.f);
    float p = v * Wo[lane];
    for (int d = 32; d > 0; d >>= 1) p += __shfl_xor(p, d);
    if (lane == 0) out[node] = p + bo[0];
}

// ---------------- launch ----------------

extern "C" void kernel_launch(void* const* d_in, const int* in_sizes, int n_in,
                              void* d_out, int out_size, void* d_ws, size_t ws_size,
                              hipStream_t stream) {
    const float* x   = (const float*)d_in[0];
    const int*   ei  = (const int*)d_in[1];
    const float* Wl0 = (const float*)d_in[2];
    const float* bl0 = (const float*)d_in[3];
    const float* Wr0 = (const float*)d_in[4];
    const float* g0  = (const float*)d_in[5];
    const float* be0 = (const float*)d_in[6];
    const float* Wl1 = (const float*)d_in[7];
    const float* bl1 = (const float*)d_in[8];
    const float* Wr1 = (const float*)d_in[9];
    const float* g1  = (const float*)d_in[10];
    const float* be1 = (const float*)d_in[11];
    const float* Wl2 = (const float*)d_in[12];
    const float* bl2 = (const float*)d_in[13];
    const float* Wr2 = (const float*)d_in[14];
    const float* g2  = (const float*)d_in[15];
    const float* be2 = (const float*)d_in[16];
    const float* Wo  = (const float*)d_in[17];
    const float* bo  = (const float*)d_in[18];

    const int N = in_sizes[0] / 7;
    const int E = in_sizes[1] / 2;
    const int* srcp = ei;
    const int* dstp = ei + E;

    char* ws = (char*)d_ws;
    size_t off = 0;
    auto walloc = [&](size_t bytes) -> void* {
        void* p = ws + off;
        off = (off + bytes + 255) & ~(size_t)255;
        return p;
    };
    int*   cnt     = (int*)walloc((size_t)(N + 1) * sizeof(int));  // cursor at cnt[N]
    int*   cursor  = cnt + N;
    int*   start   = (int*)walloc((size_t)N * sizeof(int));
    int*   fillcur = (int*)walloc((size_t)N * sizeof(int));
    int*   col     = (int*)walloc((size_t)E * sizeof(int) + 64);   // +slack for batch over-read
    float* sums    = (float*)walloc(3 * 128 * sizeof(float));
    float* scale   = (float*)walloc(3 * 64 * sizeof(float));
    float* shift   = (float*)walloc(3 * 64 * sizeof(float));
    float* h0      = (float*)walloc((size_t)N * 64 * sizeof(float));
    float* h1      = (float*)walloc((size_t)N * 64 * sizeof(float));

    hipMemsetAsync(cnt, 0, (size_t)(N + 1) * sizeof(int), stream);
    hipMemsetAsync(sums, 0, 3 * 128 * sizeof(float), stream);

    const int tb = 256;
    hist_kernel<<<(E + tb - 1) / tb, tb, 0, stream>>>(dstp, cnt, E);
    alloc_kernel<<<(N + tb - 1) / tb, tb, 0, stream>>>(cnt, start, fillcur, cursor, N);
    fill_kernel<<<(E + tb - 1) / tb, tb, 0, stream>>>(srcp, dstp, fillcur, col, E);

    const int gb = (N + 7) / 8;

    fused_layer<7, false><<<gb, 512, 0, stream>>>(x, nullptr, nullptr, col, start, cnt,
                                                  Wl0, bl0, Wr0, h0, N);
    bn_stats<<<1024, 256, 0, stream>>>(h0, sums, N);
    bn_finalize<<<1, 64, 0, stream>>>(sums, g0, be0, scale, shift, N);

    fused_layer<64, true><<<gb, 512, 0, stream>>>(h0, scale, shift, col, start, cnt,
                                                  Wl1, bl1, Wr1, h1, N);
    bn_stats<<<1024, 256, 0, stream>>>(h1, sums + 128, N);
    bn_finalize<<<1, 64, 0, stream>>>(sums + 128, g1, be1, scale + 64, shift + 64, N);

    fused_layer<64, true><<<gb, 512, 0, stream>>>(h1, scale + 64, shift + 64, col, start, cnt,
                                                  Wl2, bl2, Wr2, h0, N);
    bn_stats<<<1024, 256, 0, stream>>>(h0, sums + 256, N);
    bn_finalize<<<1, 64, 0, stream>>>(sums + 256, g2, be2, scale + 128, shift + 128, N);

    out_kernel<<<(N + 3) / 4, 256, 0, stream>>>(h0, scale + 128, shift + 128, Wo, bo, (float*)d_out, N);
}

// Round 3
// 730.421 us; speedup vs baseline: 1.3841x; 1.0872x over previous
//
#include <hip/hip_runtime.h>

#define NCOL 64
#define EPSV 1e-5f

// ---------------- CSR build ----------------

__global__ void hist_kernel(const int* __restrict__ dst, int* __restrict__ cnt, int E) {
    int i = blockIdx.x * blockDim.x + threadIdx.x;
    if (i < E) atomicAdd(&cnt[dst[i]], 1);
}

// Wave-aggregated segment allocation: one global atomic per wave (~1.6K total).
__global__ void alloc_kernel(const int* __restrict__ cnt, int2* __restrict__ seg,
                             int* __restrict__ fillcur, int* __restrict__ cursor, int n) {
    int i = blockIdx.x * blockDim.x + threadIdx.x;
    int lane = threadIdx.x & 63;
    int c = (i < n) ? cnt[i] : 0;
    int pre = c;
    for (int d = 1; d < 64; d <<= 1) {
        int t = __shfl_up(pre, d);
        if (lane >= d) pre += t;
    }
    int excl = pre - c;
    int total = __shfl(pre, 63);
    int base = 0;
    if (lane == 0) base = atomicAdd(cursor, total);
    base = __shfl(base, 0);
    if (i < n) { seg[i] = make_int2(base + excl, c); fillcur[i] = base + excl; }
}

__global__ void fill_kernel(const int* __restrict__ src, const int* __restrict__ dst,
                            int* __restrict__ fillcur, int* __restrict__ col, int E) {
    int i = blockIdx.x * blockDim.x + threadIdx.x;
    if (i < E) {
        int p = atomicAdd(&fillcur[dst[i]], 1);
        col[p] = src[i];
    }
}

// ---------------- fused SAGE layer, DIN=64, persistent ----------------
// One wave per node (grid-stride); lane = output column. Weights staged in LDS
// once per block. Gather batched 8-deep for MLP.

template <bool PRENORM>
__global__ __launch_bounds__(512) void fused_layer64(
    const float* __restrict__ xin, const float* __restrict__ scale, const float* __restrict__ shift,
    const int* __restrict__ col, const int2* __restrict__ seg,
    const float* __restrict__ Wl, const float* __restrict__ bl, const float* __restrict__ Wr,
    float* __restrict__ hout, int n)
{
    __shared__ float sWl[64 * NCOL];
    __shared__ float sWr[64 * NCOL];
    for (int i = threadIdx.x; i < 64 * NCOL; i += 512) { sWl[i] = Wl[i]; sWr[i] = Wr[i]; }
    __syncthreads();

    int lane = threadIdx.x & 63;
    float scl = 1.f, shf = 0.f;
    if (PRENORM) { scl = scale[lane]; shf = shift[lane]; }
    float blv = bl[lane];

    int wv = blockIdx.x * 8 + (threadIdx.x >> 6);
    int nw = gridDim.x * 8;

    for (int node0 = wv; node0 < n; node0 += nw) {
        int node = __builtin_amdgcn_readfirstlane(node0);
        int2 sc = seg[node];
        int s0  = __builtin_amdgcn_readfirstlane(sc.x);
        int deg = __builtin_amdgcn_readfirstlane(sc.y);
        const int* __restrict__ cp = col + s0;

        float xself = xin[(size_t)node * 64 + lane];
        if (PRENORM) xself = fmaxf(xself * scl + shf, 0.f);

        float a0 = 0.f, a1 = 0.f, a2 = 0.f, a3 = 0.f;
        float a4 = 0.f, a5 = 0.f, a6 = 0.f, a7 = 0.f;
        for (int j0 = 0; j0 < deg; j0 += 8) {
            // Over-reads are clamped and predicated to zero.
            int i0 = cp[j0 + 0], i1 = cp[j0 + 1], i2 = cp[j0 + 2], i3 = cp[j0 + 3];
            int i4 = cp[j0 + 4], i5 = cp[j0 + 5], i6 = cp[j0 + 6], i7 = cp[j0 + 7];
            i0 = min(max(i0, 0), n - 1); i1 = min(max(i1, 0), n - 1);
            i2 = min(max(i2, 0), n - 1); i3 = min(max(i3, 0), n - 1);
            i4 = min(max(i4, 0), n - 1); i5 = min(max(i5, 0), n - 1);
            i6 = min(max(i6, 0), n - 1); i7 = min(max(i7, 0), n - 1);
            float v0 = xin[(size_t)i0 * 64 + lane], v1 = xin[(size_t)i1 * 64 + lane];
            float v2 = xin[(size_t)i2 * 64 + lane], v3 = xin[(size_t)i3 * 64 + lane];
            float v4 = xin[(size_t)i4 * 64 + lane], v5 = xin[(size_t)i5 * 64 + lane];
            float v6 = xin[(size_t)i6 * 64 + lane], v7 = xin[(size_t)i7 * 64 + lane];
            if (PRENORM) {
                v0 = fmaxf(v0 * scl + shf, 0.f); v1 = fmaxf(v1 * scl + shf, 0.f);
                v2 = fmaxf(v2 * scl + shf, 0.f); v3 = fmaxf(v3 * scl + shf, 0.f);
                v4 = fmaxf(v4 * scl + shf, 0.f); v5 = fmaxf(v5 * scl + shf, 0.f);
                v6 = fmaxf(v6 * scl + shf, 0.f); v7 = fmaxf(v7 * scl + shf, 0.f);
            }
            a0 += v0;
            a1 += (j0 + 1 < deg) ? v1 : 0.f;
            a2 += (j0 + 2 < deg) ? v2 : 0.f;
            a3 += (j0 + 3 < deg) ? v3 : 0.f;
            a4 += (j0 + 4 < deg) ? v4 : 0.f;
            a5 += (j0 + 5 < deg) ? v5 : 0.f;
            a6 += (j0 + 6 < deg) ? v6 : 0.f;
            a7 += (j0 + 7 < deg) ? v7 : 0.f;
        }
        float acc = (((a0 + a1) + (a2 + a3)) + ((a4 + a5) + (a6 + a7))) * (1.f / (float)max(deg, 1));

        float h = blv;
#pragma unroll
        for (int k = 0; k < 64; ++k) {
            float ak = __shfl(acc, k);
            float xk = __shfl(xself, k);
            h += ak * sWl[k * NCOL + lane] + xk * sWr[k * NCOL + lane];
        }
        hout[(size_t)node * NCOL + lane] = h;
    }
}

// ---------------- fused SAGE layer, DIN=7, persistent ----------------
// 8 lanes per neighbor: lane = 8*g + c loads xin[idx_g*7 + c]. One load
// instruction fetches 8 neighbors; group-reduce via shfl_xor(8/16/32).

__global__ __launch_bounds__(512) void fused_layer7(
    const float* __restrict__ xin,
    const int* __restrict__ col, const int2* __restrict__ seg,
    const float* __restrict__ Wl, const float* __restrict__ bl, const float* __restrict__ Wr,
    float* __restrict__ hout, int n)
{
    __shared__ float sWl[7 * NCOL];
    __shared__ float sWr[7 * NCOL];
    for (int i = threadIdx.x; i < 7 * NCOL; i += 512) { sWl[i] = Wl[i]; sWr[i] = Wr[i]; }
    __syncthreads();

    int lane = threadIdx.x & 63;
    int g = lane >> 3, c = lane & 7;
    float blv = bl[lane];

    int wv = blockIdx.x * 8 + (threadIdx.x >> 6);
    int nw = gridDim.x * 8;

    for (int node0 = wv; node0 < n; node0 += nw) {
        int node = __builtin_amdgcn_readfirstlane(node0);
        int2 sc = seg[node];
        int s0  = __builtin_amdgcn_readfirstlane(sc.x);
        int deg = __builtin_amdgcn_readfirstlane(sc.y);

        float xself = (lane < 7) ? xin[(size_t)node * 7 + lane] : 0.f;

        float acc = 0.f;
        for (int j0 = 0; j0 < deg; j0 += 16) {
            int jA = min(j0 + g, deg - 1);
            int jB = min(j0 + 8 + g, deg - 1);
            int iA = col[s0 + jA];
            int iB = col[s0 + jB];
            float vA = (c < 7) ? xin[(size_t)iA * 7 + c] : 0.f;
            float vB = (c < 7) ? xin[(size_t)iB * 7 + c] : 0.f;
            acc += (j0 + g < deg) ? vA : 0.f;
            acc += (j0 + 8 + g < deg) ? vB : 0.f;
        }
        acc += __shfl_xor(acc, 8);
        acc += __shfl_xor(acc, 16);
        acc += __shfl_xor(acc, 32);   // every lane: sum of column c
        acc *= 1.f / (float)max(deg, 1);

        float h = blv;
#pragma unroll
        for (int k = 0; k < 7; ++k) {
            float ak = __shfl(acc, k);    // lane k holds column k (k<8)
            float xk = __shfl(xself, k);
            h += ak * sWl[k * NCOL + lane] + xk * sWr[k * NCOL + lane];
        }
        hout[(size_t)node * NCOL + lane] = h;
    }
}

// ---------------- BN statistics ----------------

__global__ __launch_bounds__(256) void bn_stats(const float* __restrict__ h,
                                                float* __restrict__ sums, int n) {
    __shared__ float ls[128];
    if (threadIdx.x < 128) ls[threadIdx.x] = 0.f;
    __syncthreads();
    size_t total = (size_t)n * 64;
    size_t stride = (size_t)gridDim.x * 1024;
    float s0 = 0.f, s1 = 0.f, s2 = 0.f, s3 = 0.f;
    float q0 = 0.f, q1 = 0.f, q2 = 0.f, q3 = 0.f;
    for (size_t i = (size_t)blockIdx.x * 1024 + (size_t)threadIdx.x * 4; i < total; i += stride) {
        float4 v = *reinterpret_cast<const float4*>(h + i);
        s0 += v.x; q0 += v.x * v.x;
        s1 += v.y; q1 += v.y * v.y;
        s2 += v.z; q2 += v.z * v.z;
        s3 += v.w; q3 += v.w * v.w;
    }
    int c = (threadIdx.x * 4) & 63;
    atomicAdd(&ls[c + 0], s0); atomicAdd(&ls[c + 1], s1);
    atomicAdd(&ls[c + 2], s2); atomicAdd(&ls[c + 3], s3);
    atomicAdd(&ls[64 + c + 0], q0); atomicAdd(&ls[64 + c + 1], q1);
    atomicAdd(&ls[64 + c + 2], q2); atomicAdd(&ls[64 + c + 3], q3);
    __syncthreads();
    if (threadIdx.x < 128) atomicAdd(&sums[threadIdx.x], ls[threadIdx.x]);
}

__global__ void bn_finalize(const float* __restrict__ sums, const float* __restrict__ g,
                            const float* __restrict__ be, float* __restrict__ scale,
                            float* __restrict__ shift, int n) {
    int c = threadIdx.x;
    if (c < 64) {
        float inv_n = 1.f / (float)n;
        float mu = sums[c] * inv_n;
        float var = sums[64 + c] * inv_n - mu * mu;
        float sc = g[c] * rsqrtf(var + EPSV);
        scale[c] = sc;
        shift[c] = be[c] - mu * sc;
    }
}

// ---------------- output head: relu(BN(h)) @ Wo + bo ----------------

__global__ __launch_bounds__(256) void out_kernel(const float* __restrict__ h,
                                                  const float* __restrict__ scale,
                                                  const float* __restrict__ shift,
                                                  const float* __restrict__ Wo,
                                                  const float* __restrict__ bo,
                                                  float* __restrict__ out, int n) {
    int lane = threadIdx.x & 63;
    int wave = threadIdx.x >> 6;
    int node = blockIdx.x * 4 + wave;
    if (node >= n) return;
    float v = h[(size_t)node * 64 + lane];
    v = fmaxf(v * scale[lane] + shift[lane], 0.f);
    float p = v * Wo[lane];
    for (int d = 32; d > 0; d >>= 1) p += __shfl_xor(p, d);
    if (lane == 0) out[node] = p + bo[0];
}

// ---------------- launch ----------------

extern "C" void kernel_launch(void* const* d_in, const int* in_sizes, int n_in,
                              void* d_out, int out_size, void* d_ws, size_t ws_size,
                              hipStream_t stream) {
    const float* x   = (const float*)d_in[0];
    const int*   ei  = (const int*)d_in[1];
    const float* Wl0 = (const float*)d_in[2];
    const float* bl0 = (const float*)d_in[3];
    const float* Wr0 = (const float*)d_in[4];
    const float* g0  = (const float*)d_in[5];
    const float* be0 = (const float*)d_in[6];
    const float* Wl1 = (const float*)d_in[7];
    const float* bl1 = (const float*)d_in[8];
    const float* Wr1 = (const float*)d_in[9];
    const float* g1  = (const float*)d_in[10];
    const float* be1 = (const float*)d_in[11];
    const float* Wl2 = (const float*)d_in[12];
    const float* bl2 = (const float*)d_in[13];
    const float* Wr2 = (const float*)d_in[14];
    const float* g2  = (const float*)d_in[15];
    const float* be2 = (const float*)d_in[16];
    const float* Wo  = (const float*)d_in[17];
    const float* bo  = (const float*)d_in[18];

    const int N = in_sizes[0] / 7;
    const int E = in_sizes[1] / 2;
    const int* srcp = ei;
    const int* dstp = ei + E;

    char* ws = (char*)d_ws;
    size_t off = 0;
    auto walloc = [&](size_t bytes) -> void* {
        void* p = ws + off;
        off = (off + bytes + 255) & ~(size_t)255;
        return p;
    };
    int*   cnt     = (int*)walloc((size_t)(N + 1) * sizeof(int));  // cursor at cnt[N]
    int*   cursor  = cnt + N;
    int2*  seg     = (int2*)walloc((size_t)N * sizeof(int2));
    int*   fillcur = (int*)walloc((size_t)N * sizeof(int));
    int*   col     = (int*)walloc((size_t)E * sizeof(int) + 64);   // +slack for batch over-read
    float* sums    = (float*)walloc(3 * 128 * sizeof(float));
    float* scale   = (float*)walloc(3 * 64 * sizeof(float));
    float* shift   = (float*)walloc(3 * 64 * sizeof(float));
    float* h0      = (float*)walloc((size_t)N * 64 * sizeof(float));
    float* h1      = (float*)walloc((size_t)N * 64 * sizeof(float));

    hipMemsetAsync(cnt, 0, (size_t)(N + 1) * sizeof(int), stream);
    hipMemsetAsync(sums, 0, 3 * 128 * sizeof(float), stream);

    const int tb = 256;
    hist_kernel<<<(E + tb - 1) / tb, tb, 0, stream>>>(dstp, cnt, E);
    alloc_kernel<<<(N + tb - 1) / tb, tb, 0, stream>>>(cnt, seg, fillcur, cursor, N);
    fill_kernel<<<(E + tb - 1) / tb, tb, 0, stream>>>(srcp, dstp, fillcur, col, E);

    const int PG = 1024;  // 4 blocks/CU x 256 CUs

    fused_layer7<<<PG, 512, 0, stream>>>(x, col, seg, Wl0, bl0, Wr0, h0, N);
    bn_stats<<<1024, 256, 0, stream>>>(h0, sums, N);
    bn_finalize<<<1, 64, 0, stream>>>(sums, g0, be0, scale, shift, N);

    fused_layer64<true><<<PG, 512, 0, stream>>>(h0, scale, shift, col, seg,
                                                Wl1, bl1, Wr1, h1, N);
    bn_stats<<<1024, 256, 0, stream>>>(h1, sums + 128, N);
    bn_finalize<<<1, 64, 0, stream>>>(sums + 128, g1, be1, scale + 64, shift + 64, N);

    fused_layer64<true><<<PG, 512, 0, stream>>>(h1, scale + 64, shift + 64, col, seg,
                                                Wl2, bl2, Wr2, h0, N);
    bn_stats<<<1024, 256, 0, stream>>>(h0, sums + 256, N);
    bn_finalize<<<1, 64, 0, stream>>>(sums + 256, g2, be2, scale + 128, shift + 128, N);

    out_kernel<<<(N + 3) / 4, 256, 0, stream>>>(h0, scale + 128, shift + 128, Wo, bo, (float*)d_out, N);
}

// Round 4
// 600.317 us; speedup vs baseline: 1.6841x; 1.2167x over previous
//
#include <hip/hip_runtime.h>

#define EPSV 1e-5f

// ---------------- CSR build (segments padded to multiple of 8 with index n) ----------------

__global__ void hist_kernel(const int* __restrict__ dst, int* __restrict__ cnt, int E) {
    int i = blockIdx.x * blockDim.x + threadIdx.x;
    if (i < E) atomicAdd(&cnt[dst[i]], 1);
}

__global__ void alloc_kernel(const int* __restrict__ cnt, int2* __restrict__ seg,
                             int* __restrict__ fillcur, int* __restrict__ cursor,
                             int* __restrict__ col, int n) {
    int i = blockIdx.x * blockDim.x + threadIdx.x;
    int lane = threadIdx.x & 63;
    int c = (i < n) ? cnt[i] : 0;
    int pc = (c + 7) & ~7;                       // padded length
    int pre = pc;
    for (int d = 1; d < 64; d <<= 1) {
        int t = __shfl_up(pre, d);
        if (lane >= d) pre += t;
    }
    int excl = pre - pc;
    int total = __shfl(pre, 63);
    int base = 0;
    if (lane == 0) base = atomicAdd(cursor, total);
    base = __shfl(base, 0);
    if (i < n) {
        int s0 = base + excl;
        seg[i] = make_int2(s0, c);
        fillcur[i] = s0;
        for (int j = c; j < pc; ++j) col[s0 + j] = n;   // pads -> zero row
    }
}

__global__ void fill_kernel(const int* __restrict__ src, const int* __restrict__ dst,
                            int* __restrict__ fillcur, int* __restrict__ col, int E) {
    int i = blockIdx.x * blockDim.x + threadIdx.x;
    if (i < E) {
        int p = atomicAdd(&fillcur[dst[i]], 1);
        col[p] = src[i];
    }
}

// ---------------- transform, DIN=7: y_l = x@Wl ; hpart = x@Wr + bl ----------------

__global__ __launch_bounds__(512) void transform7(
    const float* __restrict__ x,
    const float* __restrict__ Wl, const float* __restrict__ bl, const float* __restrict__ Wr,
    float* __restrict__ yl, float* __restrict__ hpart, int n)
{
    __shared__ float swl[7 * 64], swr[7 * 64], sbl[64];
    for (int i = threadIdx.x; i < 7 * 64; i += 512) { swl[i] = Wl[i]; swr[i] = Wr[i]; }
    if (threadIdx.x < 64) sbl[threadIdx.x] = bl[threadIdx.x];
    __syncthreads();

    // zero row n of yl (pad target) once
    if (blockIdx.x == 0 && threadIdx.x < 64) yl[(size_t)n * 64 + threadIdx.x] = 0.f;

    int lane = threadIdx.x & 63;
    int node = blockIdx.x * 8 + (threadIdx.x >> 6);
    if (node >= n) return;

    float xv = (lane < 7) ? x[(size_t)node * 7 + lane] : 0.f;
    float hl = 0.f, hr = sbl[lane];
#pragma unroll
    for (int k = 0; k < 7; ++k) {
        float xk = __shfl(xv, k);
        hl += xk * swl[k * 64 + lane];
        hr += xk * swr[k * 64 + lane];
    }
    yl[(size_t)node * 64 + lane] = hl;
    hpart[(size_t)node * 64 + lane] = hr;
}

// ---------------- transform, DIN=64: z = relu(BN(zin)); y_l = z@Wl ; hpart = z@Wr + bl ----
// 64-node tile per 256-thread block. Thread owns 4 nodes x 8 cols (register blocked).
// z reads are LDS broadcasts; weight reads are float4.

__global__ __launch_bounds__(256) void transform64(
    const float* __restrict__ zin, const float* __restrict__ scale, const float* __restrict__ shift,
    const float* __restrict__ Wl, const float* __restrict__ Wr, const float* __restrict__ bl,
    float* __restrict__ yl, float* __restrict__ hpart, int n)
{
    __shared__ float zt[64][68];
    __shared__ float swl[64 * 64];
    __shared__ float swr[64 * 64];
    __shared__ float ssc[64], ssh[64], sbl[64];

    int t = threadIdx.x;
    if (t < 64) { ssc[t] = scale[t]; ssh[t] = shift[t]; sbl[t] = bl[t]; }
    for (int i = t; i < 4096; i += 256) { swl[i] = Wl[i]; swr[i] = Wr[i]; }
    __syncthreads();

    int node0 = blockIdx.x * 64;
    // stage z tile with prenorm+relu applied; thread t covers node m=t>>2, cols (t&3)*16..+15
    {
        int m = t >> 2, c4 = (t & 3) * 16;
        int gm = node0 + m;
        if (gm < n) {
            const float4* zp = reinterpret_cast<const float4*>(zin + (size_t)gm * 64 + c4);
#pragma unroll
            for (int j = 0; j < 4; ++j) {
                float4 v = zp[j];
                int c = c4 + j * 4;
                v.x = fmaxf(v.x * ssc[c + 0] + ssh[c + 0], 0.f);
                v.y = fmaxf(v.y * ssc[c + 1] + ssh[c + 1], 0.f);
                v.z = fmaxf(v.z * ssc[c + 2] + ssh[c + 2], 0.f);
                v.w = fmaxf(v.w * ssc[c + 3] + ssh[c + 3], 0.f);
                zt[m][c + 0] = v.x; zt[m][c + 1] = v.y; zt[m][c + 2] = v.z; zt[m][c + 3] = v.w;
            }
        } else {
#pragma unroll
            for (int j = 0; j < 16; ++j) zt[m][c4 + j] = 0.f;
        }
    }
    __syncthreads();

    int ng = t >> 4;            // node group 0..15 -> nodes ng*4..+3
    int cg = t & 15;            // col group: cg<8 -> Wl cols, cg>=8 -> Wr cols
    int mb = ng * 4;
    const float* sw = (cg < 8) ? swl : swr;
    int c0 = (cg & 7) * 8;

    float acc[4][8];
#pragma unroll
    for (int i = 0; i < 4; ++i)
#pragma unroll
        for (int j = 0; j < 8; ++j) acc[i][j] = 0.f;

#pragma unroll 4
    for (int k = 0; k < 64; ++k) {
        float z0 = zt[mb + 0][k];
        float z1 = zt[mb + 1][k];
        float z2 = zt[mb + 2][k];
        float z3 = zt[mb + 3][k];
        float4 wa = *reinterpret_cast<const float4*>(sw + k * 64 + c0);
        float4 wb = *reinterpret_cast<const float4*>(sw + k * 64 + c0 + 4);
        float w[8] = {wa.x, wa.y, wa.z, wa.w, wb.x, wb.y, wb.z, wb.w};
#pragma unroll
        for (int j = 0; j < 8; ++j) {
            acc[0][j] += z0 * w[j];
            acc[1][j] += z1 * w[j];
            acc[2][j] += z2 * w[j];
            acc[3][j] += z3 * w[j];
        }
    }

    float* outb = (cg < 8) ? yl : hpart;
#pragma unroll
    for (int i = 0; i < 4; ++i) {
        int gm = node0 + mb + i;
        if (gm < n) {
            float o[8];
#pragma unroll
            for (int j = 0; j < 8; ++j)
                o[j] = acc[i][j] + ((cg < 8) ? 0.f : sbl[c0 + j]);
            float* dp = outb + (size_t)gm * 64 + c0;
            *reinterpret_cast<float4*>(dp)     = make_float4(o[0], o[1], o[2], o[3]);
            *reinterpret_cast<float4*>(dp + 4) = make_float4(o[4], o[5], o[6], o[7]);
        }
    }
}

// ---------------- gather: h[i] = hpart[i] + mean_j yl[col_j] ----------------
// One wave per node; lane = column. Padded CSR -> branchless 8-deep batches.

__global__ __launch_bounds__(512) void gather_kernel(
    const float* __restrict__ yl, float* __restrict__ h,
    const int* __restrict__ col, const int2* __restrict__ seg, int n)
{
    int lane = threadIdx.x & 63;
    int node = blockIdx.x * 8 + (threadIdx.x >> 6);
    if (node >= n) return;

    int2 sc = seg[node];
    int s0  = __builtin_amdgcn_readfirstlane(sc.x);
    int deg = __builtin_amdgcn_readfirstlane(sc.y);
    int pc  = (deg + 7) & ~7;
    const int* __restrict__ cp = col + s0;

    float a0 = 0.f, a1 = 0.f, a2 = 0.f, a3 = 0.f;
    float a4 = 0.f, a5 = 0.f, a6 = 0.f, a7 = 0.f;
    for (int j0 = 0; j0 < pc; j0 += 8) {
        int4 ia = *reinterpret_cast<const int4*>(cp + j0);
        int4 ib = *reinterpret_cast<const int4*>(cp + j0 + 4);
        int i0 = __builtin_amdgcn_readfirstlane(ia.x);
        int i1 = __builtin_amdgcn_readfirstlane(ia.y);
        int i2 = __builtin_amdgcn_readfirstlane(ia.z);
        int i3 = __builtin_amdgcn_readfirstlane(ia.w);
        int i4 = __builtin_amdgcn_readfirstlane(ib.x);
        int i5 = __builtin_amdgcn_readfirstlane(ib.y);
        int i6 = __builtin_amdgcn_readfirstlane(ib.z);
        int i7 = __builtin_amdgcn_readfirstlane(ib.w);
        a0 += yl[(size_t)i0 * 64 + lane];
        a1 += yl[(size_t)i1 * 64 + lane];
        a2 += yl[(size_t)i2 * 64 + lane];
        a3 += yl[(size_t)i3 * 64 + lane];
        a4 += yl[(size_t)i4 * 64 + lane];
        a5 += yl[(size_t)i5 * 64 + lane];
        a6 += yl[(size_t)i6 * 64 + lane];
        a7 += yl[(size_t)i7 * 64 + lane];
    }
    float agg = (((a0 + a1) + (a2 + a3)) + ((a4 + a5) + (a6 + a7))) * (1.f / (float)max(deg, 1));
    h[(size_t)node * 64 + lane] += agg;
}

// ---------------- BN statistics ----------------

__global__ __launch_bounds__(256) void bn_stats(const float* __restrict__ h,
                                                float* __restrict__ sums, int n) {
    __shared__ float ls[128];
    if (threadIdx.x < 128) ls[threadIdx.x] = 0.f;
    __syncthreads();
    size_t total = (size_t)n * 64;
    size_t stride = (size_t)gridDim.x * 1024;
    float s0 = 0.f, s1 = 0.f, s2 = 0.f, s3 = 0.f;
    float q0 = 0.f, q1 = 0.f, q2 = 0.f, q3 = 0.f;
    for (size_t i = (size_t)blockIdx.x * 1024 + (size_t)threadIdx.x * 4; i < total; i += stride) {
        float4 v = *reinterpret_cast<const float4*>(h + i);
        s0 += v.x; q0 += v.x * v.x;
        s1 += v.y; q1 += v.y * v.y;
        s2 += v.z; q2 += v.z * v.z;
        s3 += v.w; q3 += v.w * v.w;
    }
    int c = (threadIdx.x * 4) & 63;
    atomicAdd(&ls[c + 0], s0); atomicAdd(&ls[c + 1], s1);
    atomicAdd(&ls[c + 2], s2); atomicAdd(&ls[c + 3], s3);
    atomicAdd(&ls[64 + c + 0], q0); atomicAdd(&ls[64 + c + 1], q1);
    atomicAdd(&ls[64 + c + 2], q2); atomicAdd(&ls[64 + c + 3], q3);
    __syncthreads();
    if (threadIdx.x < 128) atomicAdd(&sums[threadIdx.x], ls[threadIdx.x]);
}

__global__ void bn_finalize(const float* __restrict__ sums, const float* __restrict__ g,
                            const float* __restrict__ be, float* __restrict__ scale,
                            float* __restrict__ shift, int n) {
    int c = threadIdx.x;
    if (c < 64) {
        float inv_n = 1.f / (float)n;
        float mu = sums[c] * inv_n;
        float var = sums[64 + c] * inv_n - mu * mu;
        float sc = g[c] * rsqrtf(var + EPSV);
        scale[c] = sc;
        shift[c] = be[c] - mu * sc;
    }
}

// ---------------- output head: relu(BN(h)) @ Wo + bo ----------------

__global__ __launch_bounds__(256) void out_kernel(const float* __restrict__ h,
                                                  const float* __restrict__ scale,
                                                  const float* __restrict__ shift,
                                                  const float* __restrict__ Wo,
                                                  const float* __restrict__ bo,
                                                  float* __restrict__ out, int n) {
    int lane = threadIdx.x & 63;
    int wave = threadIdx.x >> 6;
    int node = blockIdx.x * 4 + wave;
    if (node >= n) return;
    float v = h[(size_t)node * 64 + lane];
    v = fmaxf(v * scale[lane] + shift[lane], 0.f);
    float p = v * Wo[lane];
    for (int d = 32; d > 0; d >>= 1) p += __shfl_xor(p, d);
    if (lane == 0) out[node] = p + bo[0];
}

// ---------------- launch ----------------

extern "C" void kernel_launch(void* const* d_in, const int* in_sizes, int n_in,
                              void* d_out, int out_size, void* d_ws, size_t ws_size,
                              hipStream_t stream) {
    const float* x   = (const float*)d_in[0];
    const int*   ei  = (const int*)d_in[1];
    const float* Wl0 = (const float*)d_in[2];
    const float* bl0 = (const float*)d_in[3];
    const float* Wr0 = (const float*)d_in[4];
    const float* g0  = (const float*)d_in[5];
    const float* be0 = (const float*)d_in[6];
    const float* Wl1 = (const float*)d_in[7];
    const float* bl1 = (const float*)d_in[8];
    const float* Wr1 = (const float*)d_in[9];
    const float* g1  = (const float*)d_in[10];
    const float* be1 = (const float*)d_in[11];
    const float* Wl2 = (const float*)d_in[12];
    const float* bl2 = (const float*)d_in[13];
    const float* Wr2 = (const float*)d_in[14];
    const float* g2  = (const float*)d_in[15];
    const float* be2 = (const float*)d_in[16];
    const float* Wo  = (const float*)d_in[17];
    const float* bo  = (const float*)d_in[18];

    const int N = in_sizes[0] / 7;
    const int E = in_sizes[1] / 2;
    const int* srcp = ei;
    const int* dstp = ei + E;

    char* ws = (char*)d_ws;
    size_t off = 0;
    auto walloc = [&](size_t bytes) -> void* {
        void* p = ws + off;
        off = (off + bytes + 255) & ~(size_t)255;
        return p;
    };
    int*   cnt     = (int*)walloc((size_t)(N + 1) * sizeof(int));  // cursor at cnt[N]
    int*   cursor  = cnt + N;
    int2*  seg     = (int2*)walloc((size_t)N * sizeof(int2));
    int*   fillcur = (int*)walloc((size_t)N * sizeof(int));
    int*   col     = (int*)walloc(((size_t)E + 7 * (size_t)N + 64) * sizeof(int)); // padded CSR
    float* sums    = (float*)walloc(3 * 128 * sizeof(float));
    float* scale   = (float*)walloc(3 * 64 * sizeof(float));
    float* shift   = (float*)walloc(3 * 64 * sizeof(float));
    float* yl      = (float*)walloc(((size_t)N + 1) * 64 * sizeof(float)); // row N = zeros
    float* h0      = (float*)walloc((size_t)N * 64 * sizeof(float));
    float* h1      = (float*)walloc((size_t)N * 64 * sizeof(float));

    hipMemsetAsync(cnt, 0, (size_t)(N + 1) * sizeof(int), stream);
    hipMemsetAsync(sums, 0, 3 * 128 * sizeof(float), stream);

    const int tb = 256;
    hist_kernel<<<(E + tb - 1) / tb, tb, 0, stream>>>(dstp, cnt, E);
    alloc_kernel<<<(N + tb - 1) / tb, tb, 0, stream>>>(cnt, seg, fillcur, cursor, col, N);
    fill_kernel<<<(E + tb - 1) / tb, tb, 0, stream>>>(srcp, dstp, fillcur, col, E);

    const int gw = (N + 7) / 8;       // wave-per-node grids (512 threads)
    const int gt = (N + 63) / 64;     // transform64 tiles

    // ---- layer 0 ----
    transform7<<<gw, 512, 0, stream>>>(x, Wl0, bl0, Wr0, yl, h0, N);
    gather_kernel<<<gw, 512, 0, stream>>>(yl, h0, col, seg, N);
    bn_stats<<<1024, 256, 0, stream>>>(h0, sums, N);
    bn_finalize<<<1, 64, 0, stream>>>(sums, g0, be0, scale, shift, N);

    // ---- layer 1 ----
    transform64<<<gt, 256, 0, stream>>>(h0, scale, shift, Wl1, Wr1, bl1, yl, h1, N);
    gather_kernel<<<gw, 512, 0, stream>>>(yl, h1, col, seg, N);
    bn_stats<<<1024, 256, 0, stream>>>(h1, sums + 128, N);
    bn_finalize<<<1, 64, 0, stream>>>(sums + 128, g1, be1, scale + 64, shift + 64, N);

    // ---- layer 2 ----
    transform64<<<gt, 256, 0, stream>>>(h1, scale + 64, shift + 64, Wl2, Wr2, bl2, yl, h0, N);
    gather_kernel<<<gw, 512, 0, stream>>>(yl, h0, col, seg, N);
    bn_stats<<<1024, 256, 0, stream>>>(h0, sums + 256, N);
    bn_finalize<<<1, 64, 0, stream>>>(sums + 256, g2, be2, scale + 128, shift + 128, N);

    out_kernel<<<(N + 3) / 4, 256, 0, stream>>>(h0, scale + 128, shift + 128, Wo, bo, (float*)d_out, N);
}